// Round 15
// baseline (507.016 us; speedup 1.0000x reference)
//
#include <hip/hip_runtime.h>
#include <math.h>

#define N_NODES 50000
#define N_EDGES 400000
#define E_HALF  200000
#define D 128

// ---------------------------------------------------------------------------
// gemm_multi: fp32 GEMM  O[g] = act(x) @ W[g], g = 0..NG-1, NG even.
// x: [N,128] row-major, W: [128,128] row-major, O: [N,128].
//
// Round-14 post-mortem: 8x8 tile nulled (131us, VALUBusy 39.5%) -> kernel is
// LATENCY-bound at 2 waves/SIMD, and LDS pipe (85B/cyc) was only relieved
// 0.89x, not 1.5x. This version PAIRS two gemms per k-pass:
//   - x-fragment reads shared by both -> 6 ds_read_b128 per 128 FMAs
//     (0.75 B/FMA), two independent FMA streams (2x ILP behind loads).
//   - W chunks double-buffered (ws[2][2][4][128], 8KB): stage chunk kc+1
//     during compute of kc, ONE barrier per chunk.
//   - LDS 75.8KB -> 2 blocks/CU (8 waves) unchanged; VGPR ~176 (128 acc).
// Per-CU model: LDS 576 cyc vs VALU 512 cyc per k2 -> balanced (was 1.5x).
// In-place safe (O[g] == x): whole x tile staged to LDS before any write.
// ---------------------------------------------------------------------------
template <int NG, int RELU_IN>
__global__ __launch_bounds__(256) void gemm_multi(
    const float* __restrict__ x,
    const float* __restrict__ W0, const float* __restrict__ W1,
    const float* __restrict__ W2, const float* __restrict__ W3,
    float* __restrict__ O0, float* __restrict__ O1,
    float* __restrict__ O2, float* __restrict__ O3)
{
    __shared__ float ws[2][2][4][128];  // [buf][mat][k-row][col]  8 KB
    __shared__ float xt[128][132];      // 67.6 KB, transposed x: xt[k][row]

    const float* Wg[4] = {W0, W1, W2, W3};
    float*       Og[4] = {O0, O1, O2, O3};

    const int tid  = threadIdx.x;
    const int row0 = blockIdx.x * 128;

    // stage 128-row x tile once, transposed (k-major)
    for (int i = tid * 4; i < 128 * D; i += 256 * 4) {
        const int row = i >> 7;
        const int col = i & 127;
        const int r   = row0 + row;
        float4 v;
        if (r < N_NODES) {
            v = *(const float4*)&x[(size_t)r * D + col];
        } else {
            v = make_float4(0.f, 0.f, 0.f, 0.f);
        }
        if (RELU_IN) {
            v.x = fmaxf(v.x, 0.f); v.y = fmaxf(v.y, 0.f);
            v.z = fmaxf(v.z, 0.f); v.w = fmaxf(v.w, 0.f);
        }
        xt[col + 0][row] = v.x;
        xt[col + 1][row] = v.y;
        xt[col + 2][row] = v.z;
        xt[col + 3][row] = v.w;
    }

    const int ty  = tid >> 4;         // 0..15
    const int tx  = tid & 15;         // 0..15
    const int r0  = ty * 8;           // 8 rows per thread
    const int c0a = tx * 4;           // first 4-col group
    const int c0b = 64 + tx * 4;      // second 4-col group

    // staging decomposition: one float4 per thread per chunk
    const int sm = tid >> 7;          // 0..1  (which matrix)
    const int si = (tid & 127) * 4;   // 0..508 within 4x128 floats
    const int sr = si >> 7;           // k-row within chunk (0..3)
    const int sc = si & 127;          // col

    #pragma unroll
    for (int gp = 0; gp < NG / 2; ++gp) {
        const float* WA = Wg[2 * gp];
        const float* WB = Wg[2 * gp + 1];
        const float* Wp = (sm == 0) ? WA : WB;

        float accA[8][8], accB[8][8];
        #pragma unroll
        for (int r = 0; r < 8; ++r)
            #pragma unroll
            for (int c = 0; c < 8; ++c) { accA[r][c] = 0.f; accB[r][c] = 0.f; }

        // prologue: stage chunk 0 -> buf0
        *(float4*)&ws[0][sm][sr][sc] = *(const float4*)&Wp[(size_t)sr * D + sc];
        __syncthreads();

        #pragma unroll 1
        for (int kc = 0; kc < 32; kc += 2) {
            // --- chunk kc from buf0; stage kc+1 -> buf1 ---
            if (kc + 1 < 32) {
                *(float4*)&ws[1][sm][sr][sc] =
                    *(const float4*)&Wp[(size_t)(kc + 1) * 4 * D + sr * D + sc];
            }
            {
                const int kbase = kc * 4;
                #pragma unroll
                for (int k2 = 0; k2 < 4; ++k2) {
                    const float4 wa0 = *(const float4*)&ws[0][0][k2][c0a];
                    const float4 wb0 = *(const float4*)&ws[0][0][k2][c0b];
                    const float4 wa1 = *(const float4*)&ws[0][1][k2][c0a];
                    const float4 wb1 = *(const float4*)&ws[0][1][k2][c0b];
                    const float4 x0  = *(const float4*)&xt[kbase + k2][r0];
                    const float4 x1  = *(const float4*)&xt[kbase + k2][r0 + 4];
                    const float wv0[8] = {wa0.x, wa0.y, wa0.z, wa0.w,
                                          wb0.x, wb0.y, wb0.z, wb0.w};
                    const float wv1[8] = {wa1.x, wa1.y, wa1.z, wa1.w,
                                          wb1.x, wb1.y, wb1.z, wb1.w};
                    const float xr[8]  = {x0.x, x0.y, x0.z, x0.w,
                                          x1.x, x1.y, x1.z, x1.w};
                    #pragma unroll
                    for (int r = 0; r < 8; ++r) {
                        #pragma unroll
                        for (int c = 0; c < 8; ++c) {
                            accA[r][c] = fmaf(xr[r], wv0[c], accA[r][c]);
                            accB[r][c] = fmaf(xr[r], wv1[c], accB[r][c]);
                        }
                    }
                }
            }
            __syncthreads();

            // --- chunk kc+1 from buf1; stage kc+2 -> buf0 ---
            if (kc + 2 < 32) {
                *(float4*)&ws[0][sm][sr][sc] =
                    *(const float4*)&Wp[(size_t)(kc + 2) * 4 * D + sr * D + sc];
            }
            {
                const int kbase = (kc + 1) * 4;
                #pragma unroll
                for (int k2 = 0; k2 < 4; ++k2) {
                    const float4 wa0 = *(const float4*)&ws[1][0][k2][c0a];
                    const float4 wb0 = *(const float4*)&ws[1][0][k2][c0b];
                    const float4 wa1 = *(const float4*)&ws[1][1][k2][c0a];
                    const float4 wb1 = *(const float4*)&ws[1][1][k2][c0b];
                    const float4 x0  = *(const float4*)&xt[kbase + k2][r0];
                    const float4 x1  = *(const float4*)&xt[kbase + k2][r0 + 4];
                    const float wv0[8] = {wa0.x, wa0.y, wa0.z, wa0.w,
                                          wb0.x, wb0.y, wb0.z, wb0.w};
                    const float wv1[8] = {wa1.x, wa1.y, wa1.z, wa1.w,
                                          wb1.x, wb1.y, wb1.z, wb1.w};
                    const float xr[8]  = {x0.x, x0.y, x0.z, x0.w,
                                          x1.x, x1.y, x1.z, x1.w};
                    #pragma unroll
                    for (int r = 0; r < 8; ++r) {
                        #pragma unroll
                        for (int c = 0; c < 8; ++c) {
                            accA[r][c] = fmaf(xr[r], wv0[c], accA[r][c]);
                            accB[r][c] = fmaf(xr[r], wv1[c], accB[r][c]);
                        }
                    }
                }
            }
            __syncthreads();
        }

        float* OA = Og[2 * gp];
        float* OB = Og[2 * gp + 1];
        #pragma unroll
        for (int r = 0; r < 8; ++r) {
            const int row = row0 + r0 + r;
            if (row < N_NODES) {
                *(float4*)&OA[(size_t)row * D + c0a] =
                    make_float4(accA[r][0], accA[r][1], accA[r][2], accA[r][3]);
                *(float4*)&OA[(size_t)row * D + c0b] =
                    make_float4(accA[r][4], accA[r][5], accA[r][6], accA[r][7]);
                *(float4*)&OB[(size_t)row * D + c0a] =
                    make_float4(accB[r][0], accB[r][1], accB[r][2], accB[r][3]);
                *(float4*)&OB[(size_t)row * D + c0b] =
                    make_float4(accB[r][4], accB[r][5], accB[r][6], accB[r][7]);
            }
        }
    }
}

// ---------------------------------------------------------------------------
// CSR build: zero -> histogram -> 3-stage scan -> bucket scatter
// (round-13: 3-stage scan verified, scan gone from top-5)
// ---------------------------------------------------------------------------
__global__ __launch_bounds__(256) void zero_kernel(int* __restrict__ p, int n)
{
    const int i = blockIdx.x * 256 + threadIdx.x;
    if (i < n) p[i] = 0;
}

__global__ __launch_bounds__(256) void hist_kernel(
    const int* __restrict__ dst, int* __restrict__ cnt)
{
    const int e = blockIdx.x * 256 + threadIdx.x;
    if (e < N_EDGES) atomicAdd(&cnt[dst[e]], 1);
}

#define SCAN_NB 196   // ceil(50000/256)

// stage 1: per-block exclusive scan of cnt; block totals to bsum
__global__ __launch_bounds__(256) void scan_partial(
    const int* __restrict__ cnt, int* __restrict__ exc, int* __restrict__ bsum)
{
    __shared__ int sh[256];
    const int t   = threadIdx.x;
    const int idx = blockIdx.x * 256 + t;
    const int v   = (idx < N_NODES) ? cnt[idx] : 0;
    sh[t] = v;
    __syncthreads();
    #pragma unroll
    for (int d = 1; d < 256; d <<= 1) {
        const int tv = (t >= d) ? sh[t - d] : 0;
        __syncthreads();
        sh[t] += tv;
        __syncthreads();
    }
    if (idx < N_NODES) exc[idx] = sh[t] - v;
    if (t == 255) bsum[blockIdx.x] = sh[255];
}

// stage 2: one block scans the block totals
__global__ __launch_bounds__(256) void scan_block(
    const int* __restrict__ bsum, int* __restrict__ bscan)
{
    __shared__ int sh[256];
    const int t = threadIdx.x;
    const int v = (t < SCAN_NB) ? bsum[t] : 0;
    sh[t] = v;
    __syncthreads();
    #pragma unroll
    for (int d = 1; d < 256; d <<= 1) {
        const int tv = (t >= d) ? sh[t - d] : 0;
        __syncthreads();
        sh[t] += tv;
        __syncthreads();
    }
    if (t < SCAN_NB) bscan[t] = sh[t] - v;
}

// stage 3: add block offsets, emit off + cursor; off[N] is the edge total
__global__ __launch_bounds__(256) void scan_final(
    const int* __restrict__ exc, const int* __restrict__ bscan,
    int* __restrict__ off, int* __restrict__ cursor)
{
    const int idx = blockIdx.x * 256 + threadIdx.x;
    if (idx < N_NODES) {
        const int o = exc[idx] + bscan[blockIdx.x];
        off[idx]    = o;
        cursor[idx] = o;
    }
    if (idx == 0) off[N_NODES] = N_EDGES;
}

__global__ __launch_bounds__(256) void bucket_kernel(
    const int* __restrict__ src, const int* __restrict__ dst,
    int* __restrict__ cursor, int* __restrict__ csr_src, int* __restrict__ csr_eid)
{
    const int e = blockIdx.x * 256 + threadIdx.x;
    if (e >= N_EDGES) return;
    const int pos = atomicAdd(&cursor[dst[e]], 1);
    csr_src[pos] = src[e];
    csr_eid[pos] = e;
}

// ---------------------------------------------------------------------------
// gather_sum: emb[d] += sum_{e: dst=d} h[src[e]]   (one wave/node, float2/lane)
// ---------------------------------------------------------------------------
__global__ __launch_bounds__(256) void gather_sum(
    const int* __restrict__ off, const int* __restrict__ csr_src,
    const float* __restrict__ h, float* __restrict__ emb)
{
    const int t    = blockIdx.x * 256 + threadIdx.x;
    const int node = t >> 6;
    const int lane = t & 63;
    if (node >= N_NODES) return;
    const int beg = off[node];
    const int end = off[node + 1];
    const size_t o = (size_t)node * D + lane * 2;
    float2 acc = *(const float2*)&emb[o];
    for (int j = beg; j < end; ++j) {
        const int s = csr_src[j];
        const float2 v = *(const float2*)&h[(size_t)s * D + lane * 2];
        acc.x += v.x; acc.y += v.y;
    }
    *(float2*)&emb[o] = acc;
}

// ---------------------------------------------------------------------------
// gather_watt_relu: out[d] = relu(out[d] + sum 0.5*(att[e]+att[pair])*hc[src[e]])
// ---------------------------------------------------------------------------
__global__ __launch_bounds__(256) void gather_watt_relu(
    const int* __restrict__ off, const int* __restrict__ csr_src,
    const int* __restrict__ csr_eid, const float* __restrict__ att,
    const float* __restrict__ hc, float* __restrict__ out)
{
    const int t    = blockIdx.x * 256 + threadIdx.x;
    const int node = t >> 6;
    const int lane = t & 63;
    if (node >= N_NODES) return;
    const int beg = off[node];
    const int end = off[node + 1];
    const size_t o = (size_t)node * D + lane * 2;
    float2 acc = *(const float2*)&out[o];
    for (int j = beg; j < end; ++j) {
        const int s   = csr_src[j];
        const int eid = csr_eid[j];
        const int pr  = (eid < E_HALF) ? (eid + E_HALF) : (eid - E_HALF);
        const float w = 0.5f * (att[eid] + att[pr]);
        const float2 v = *(const float2*)&hc[(size_t)s * D + lane * 2];
        acc.x = fmaf(w, v.x, acc.x);
        acc.y = fmaf(w, v.y, acc.y);
    }
    acc.x = fmaxf(acc.x, 0.f);
    acc.y = fmaxf(acc.y, 0.f);
    *(float2*)&out[o] = acc;
}

// ---------------------------------------------------------------------------
// edge_logits: att[e] = sigmoid( tanh(A[src]+B[dst]) . we2 + gumbel(noise) )
// fast tanh: 1 - 2/(e^{2x}+1); correct limits at +-inf, no clamp needed.
// ---------------------------------------------------------------------------
__device__ __forceinline__ float fast_tanh(float v)
{
    const float e = __expf(2.f * v);
    return 1.f - 2.f / (e + 1.f);
}

__global__ __launch_bounds__(256) void edge_logits(
    const int* __restrict__ src, const int* __restrict__ dst,
    const float* __restrict__ A, const float* __restrict__ B,
    const float* __restrict__ we2, const float* __restrict__ noise_u,
    float* __restrict__ att)
{
    const int t    = blockIdx.x * 256 + threadIdx.x;
    const int e    = t >> 5;
    const int lane = t & 31;
    if (e >= N_EDGES) return;
    const int s = src[e];
    const int d = dst[e];
    const float4 a = *(const float4*)&A[(size_t)s * D + lane * 4];
    const float4 b = *(const float4*)&B[(size_t)d * D + lane * 4];
    const float4 w = *(const float4*)&we2[lane * 4];
    float p = fast_tanh(a.x + b.x) * w.x + fast_tanh(a.y + b.y) * w.y +
              fast_tanh(a.z + b.z) * w.z + fast_tanh(a.w + b.w) * w.w;
    #pragma unroll
    for (int off = 16; off >= 1; off >>= 1)
        p += __shfl_xor(p, off, 32);
    if (lane == 0) {
        const float u = noise_u[e];
        const float z = p + logf(u) - log1pf(-u);
        att[e] = 1.f / (1.f + __expf(-z));
    }
}

extern "C" void kernel_launch(void* const* d_in, const int* in_sizes, int n_in,
                              void* d_out, int out_size, void* d_ws, size_t ws_size,
                              hipStream_t stream)
{
    const float* x      = (const float*)d_in[0];
    const float* W1     = (const float*)d_in[1];
    const float* W2     = (const float*)d_in[2];
    const float* We1    = (const float*)d_in[3];
    const float* we2    = (const float*)d_in[4];
    const float* Wc1    = (const float*)d_in[5];
    const float* Wc2    = (const float*)d_in[6];
    const float* noiseu = (const float*)d_in[7];
    const int*   eidx   = (const int*)d_in[8];

    const int* src = eidx;
    const int* dst = eidx + N_EDGES;

    float* out = (float*)d_out;

    // workspace layout (float elements); total ~83 MB
    float* wsf = (float*)d_ws;
    float* h   = wsf;                  // [N,D]  x@W1, later A
    float* hc  = wsf +  6400000;       // [N,D]  x@Wc1
    float* emb = wsf + 12800000;       // [N,D]  x@W2 + agg, later B (in-place)
    float* att = wsf + 19200000;       // [E]
    int* ibase   = (int*)(wsf + 19600000);
    int* cnt     = ibase;              // [N]
    int* off     = ibase + 50000;      // [N+1]
    int* cursor  = ibase + 100001;     // [N]
    int* exc     = ibase + 150001;     // [N]
    int* bsum    = ibase + 200001;     // [SCAN_NB]
    int* bscan   = ibase + 200257;     // [SCAN_NB]
    int* csr_src = ibase + 262144;     // [E] (aligned)
    int* csr_eid = csr_src + N_EDGES;  // [E]

    const int row_tiles = (N_NODES + 127) / 128;        // 391
    const int edge_blk  = (N_EDGES + 255) / 256;        // 1563
    const int node_blk  = (N_NODES * 64 + 255) / 256;   // 12500
    const int elog_blk  = (N_EDGES * 32 + 255) / 256;   // 50000

    // CSR build (independent of GEMMs)
    zero_kernel<<<(N_NODES + 255) / 256, 256, 0, stream>>>(cnt, N_NODES);
    hist_kernel<<<edge_blk, 256, 0, stream>>>(dst, cnt);
    scan_partial<<<SCAN_NB, 256, 0, stream>>>(cnt, exc, bsum);
    scan_block<<<1, 256, 0, stream>>>(bsum, bscan);
    scan_final<<<SCAN_NB, 256, 0, stream>>>(exc, bscan, off, cursor);
    bucket_kernel<<<edge_blk, 256, 0, stream>>>(src, dst, cursor, csr_src, csr_eid);

    // K1: h = x@W1, emb = x@W2, hc = x@Wc1, out = x@Wc2  (x staged once)
    gemm_multi<4, 0><<<row_tiles, 256, 0, stream>>>(
        x, W1, W2, Wc1, Wc2, h, emb, hc, out);

    // K2: emb += gather-sum of h over incoming edges
    gather_sum<<<node_blk, 256, 0, stream>>>(off, csr_src, h, emb);

    // K3: A = relu(emb)@We1_top -> h ; B = relu(emb)@We1_bot -> emb (in-place)
    gemm_multi<2, 1><<<row_tiles, 256, 0, stream>>>(
        emb, We1, We1 + D * D, nullptr, nullptr, h, emb, nullptr, nullptr);

    // K4: att logits + gumbel-sigmoid
    edge_logits<<<elog_blk, 256, 0, stream>>>(src, dst, h, emb, we2, noiseu, att);

    // K5: out = relu(out + symmetrized-att-weighted gather of hc)
    gather_watt_relu<<<node_blk, 256, 0, stream>>>(off, csr_src, csr_eid, att, hc, out);
}